// Round 1
// baseline (638.547 us; speedup 1.0000x reference)
//
#include <hip/hip_runtime.h>

// ---------- problem constants ----------
#define BATCH   32768
#define SEQLEN  12
#define EMB     64
#define H       128
#define MLP     1024
#define Z       32
#define ZX      1056      // MLP + Z
#define NG      512       // 4*H gates
#define NCAT    1536      // MLP + NG  (fused GEMM1 output width)

typedef _Float16 f16x8 __attribute__((ext_vector_type(8)));
typedef float    f32x4 __attribute__((ext_vector_type(4)));

// ---------- workspace layout (bytes) ----------
#define WCAT_OFF   0u
#define W2H_OFF    3244032u
#define WHH_OFF    3506176u
#define WC_OFF     3637248u
#define BIAS2_OFF  3641344u
#define T1_OFF     3643392u
#define GB_OFF     70752256u
#define H0_OFF     137861120u
// total 146,249,728 bytes

__device__ __forceinline__ float sigf(float x) {
    return __builtin_amdgcn_rcpf(1.0f + __expf(-x));
}
__device__ __forceinline__ float tanhfast(float x) {
    return 2.0f * __builtin_amdgcn_rcpf(1.0f + __expf(-2.0f * x)) - 1.0f;
}

// ---------------------------------------------------------------------------
// prep: pack weights to fp16, fold biases.
//   wcat[n][k] (n<1024: W1 row n) (n>=1024: W_ih row n-1024, cols 0..1055)
//   w2h  = fp16(W2) [128][1024]
//   whh  = fp16(W_hh) [512][128]
//   wc[n][j] = sum_e W_ih[n][1056+e] * W_sp[e][j]        (512x2, fp32)
//   bias2[n] = b_ih[n] + b_hh[n] + sum_e W_ih[n][1056+e]*b_sp[e]
// ---------------------------------------------------------------------------
__global__ __launch_bounds__(256) void prep_kernel(
    const float* __restrict__ W_ih, const float* __restrict__ W_hh_in,
    const float* __restrict__ b_ih, const float* __restrict__ b_hh,
    const float* __restrict__ W1,   const float* __restrict__ W2,
    const float* __restrict__ W_sp, const float* __restrict__ b_sp,
    _Float16* __restrict__ wcat, _Float16* __restrict__ w2h,
    _Float16* __restrict__ whh,  float* __restrict__ wc, float* __restrict__ bias2)
{
    const int bid = blockIdx.x;
    const int tid = threadIdx.x;
    if (bid < 1536) {
        const float* src = (bid < 1024) ? (W1 + (size_t)bid * ZX)
                                        : (W_ih + (size_t)(bid - 1024) * 1120);
        _Float16* dst = wcat + (size_t)bid * ZX;
        for (int k = tid; k < ZX; k += 256) dst[k] = (_Float16)src[k];
    } else if (bid < 1664) {
        const int n = bid - 1536;
        for (int k = tid; k < MLP; k += 256)
            w2h[n * MLP + k] = (_Float16)W2[n * MLP + k];
    } else if (bid < 2176) {
        const int n = bid - 1664;
        if (tid < H) whh[n * H + tid] = (_Float16)W_hh_in[n * H + tid];
    } else {
        const int t = (bid - 2176) * 256 + tid;
        if (t < 1024) {
            const int n = t >> 1, j = t & 1;
            float s = 0.f;
            for (int e = 0; e < EMB; ++e)
                s += W_ih[(size_t)n * 1120 + ZX + e] * W_sp[e * 2 + j];
            wc[t] = s;
        } else if (t < 1536) {
            const int n = t - 1024;
            float s = b_ih[n] + b_hh[n];
            for (int e = 0; e < EMB; ++e)
                s += W_ih[(size_t)n * 1120 + ZX + e] * b_sp[e];
            bias2[n] = s;
        }
    }
}

// ---------------------------------------------------------------------------
// GEMM1: C[M=32768, N=1536] = zx[M,1056] @ wcat.T
//   zx = [enc_h_feat | z] read directly (k-tile 32 is entirely in one input:
//   33 k-tiles, last one is z)
//   n<1024 : t1 = fp16(relu(C + b1))
//   n>=1024: g_base = fp32(C + bias2)
// 128x128 block tile, 4 waves (2x2 of 64x64), 16x16x32 f16 MFMA.
// LDS rows padded to 40 halfs (80B) -> 2-way banks only (free).
// ---------------------------------------------------------------------------
__global__ __launch_bounds__(256) void gemm1_kernel(
    const float* __restrict__ enc, const float* __restrict__ zin,
    const _Float16* __restrict__ wcat,
    const float* __restrict__ bias1, const float* __restrict__ bias2g,
    _Float16* __restrict__ t1, float* __restrict__ g_base)
{
    __shared__ _Float16 s_a[128 * 40];
    __shared__ _Float16 s_b[128 * 40];

    const int tid = threadIdx.x;
    const int bn  = blockIdx.x;            // 0..11 (fastest -> A-tile L2/L3 reuse)
    const int m0  = blockIdx.y * 128;
    const int lane = tid & 63, w = tid >> 6;
    const int wm = w >> 1, wn = w & 1;
    const int l15 = lane & 15, q = lane >> 4;
    const int arow = tid >> 1, akc = (tid & 1) * 16;
    const int brow = bn * 128 + arow;      // global n row for B staging

    f32x4 acc[4][4] = {};

    for (int kt = 0; kt < 33; ++kt) {
        // prefetch into registers while previous tile is consumed
        const float* asrc = (kt < 32)
            ? enc + (size_t)(m0 + arow) * MLP + kt * 32 + akc
            : zin + (size_t)(m0 + arow) * Z + akc;
        const float4 a0 = ((const float4*)asrc)[0];
        const float4 a1 = ((const float4*)asrc)[1];
        const float4 a2 = ((const float4*)asrc)[2];
        const float4 a3 = ((const float4*)asrc)[3];
        const uint4* bsrc = (const uint4*)(wcat + (size_t)brow * ZX + kt * 32 + akc);
        const uint4 b0 = bsrc[0];
        const uint4 b1v = bsrc[1];

        f16x8 p0 = {(_Float16)a0.x, (_Float16)a0.y, (_Float16)a0.z, (_Float16)a0.w,
                    (_Float16)a1.x, (_Float16)a1.y, (_Float16)a1.z, (_Float16)a1.w};
        f16x8 p1 = {(_Float16)a2.x, (_Float16)a2.y, (_Float16)a2.z, (_Float16)a2.w,
                    (_Float16)a3.x, (_Float16)a3.y, (_Float16)a3.z, (_Float16)a3.w};

        __syncthreads();   // previous tile fully consumed
        *(f16x8*)(s_a + arow * 40 + akc)     = p0;
        *(f16x8*)(s_a + arow * 40 + akc + 8) = p1;
        *(uint4*)(s_b + arow * 40 + akc)     = b0;
        *(uint4*)(s_b + arow * 40 + akc + 8) = b1v;
        __syncthreads();

        f16x8 af[4];
        #pragma unroll
        for (int im = 0; im < 4; ++im)
            af[im] = *(const f16x8*)(s_a + (wm * 64 + im * 16 + l15) * 40 + q * 8);
        #pragma unroll
        for (int in_ = 0; in_ < 4; ++in_) {
            const f16x8 bf = *(const f16x8*)(s_b + (wn * 64 + in_ * 16 + l15) * 40 + q * 8);
            #pragma unroll
            for (int im = 0; im < 4; ++im)
                acc[im][in_] = __builtin_amdgcn_mfma_f32_16x16x32_f16(af[im], bf, acc[im][in_], 0, 0, 0);
        }
    }

    // epilogue (C layout: col = lane&15, row = (lane>>4)*4 + reg)
    if (bn < 8) {
        #pragma unroll
        for (int im = 0; im < 4; ++im)
            #pragma unroll
            for (int in_ = 0; in_ < 4; ++in_)
                #pragma unroll
                for (int r = 0; r < 4; ++r) {
                    const int m = m0 + wm * 64 + im * 16 + q * 4 + r;
                    const int n = bn * 128 + wn * 64 + in_ * 16 + l15;
                    float v = acc[im][in_][r] + bias1[n];
                    v = v > 0.f ? v : 0.f;
                    t1[(size_t)m * MLP + n] = (_Float16)v;
                }
    } else {
        #pragma unroll
        for (int im = 0; im < 4; ++im)
            #pragma unroll
            for (int in_ = 0; in_ < 4; ++in_)
                #pragma unroll
                for (int r = 0; r < 4; ++r) {
                    const int m = m0 + wm * 64 + im * 16 + q * 4 + r;
                    const int n = (bn - 8) * 128 + wn * 64 + in_ * 16 + l15;
                    g_base[(size_t)m * NG + n] = acc[im][in_][r] + bias2g[n];
                }
    }
}

// ---------------------------------------------------------------------------
// GEMM2: h0[M=32768, 128] = fp16(relu(t1[M,1024] @ w2h.T + b2))
// ---------------------------------------------------------------------------
__global__ __launch_bounds__(256) void gemm2_kernel(
    const _Float16* __restrict__ t1, const _Float16* __restrict__ w2h,
    const float* __restrict__ b2, _Float16* __restrict__ h0buf)
{
    __shared__ _Float16 s_a[128 * 40];
    __shared__ _Float16 s_b[128 * 40];

    const int tid = threadIdx.x;
    const int m0  = blockIdx.x * 128;
    const int lane = tid & 63, w = tid >> 6;
    const int wm = w >> 1, wn = w & 1;
    const int l15 = lane & 15, q = lane >> 4;
    const int arow = tid >> 1, akc = (tid & 1) * 16;

    f32x4 acc[4][4] = {};

    for (int kt = 0; kt < 32; ++kt) {
        const uint4* as = (const uint4*)(t1 + (size_t)(m0 + arow) * MLP + kt * 32 + akc);
        const uint4 a0 = as[0], a1 = as[1];
        const uint4* bs = (const uint4*)(w2h + (size_t)arow * MLP + kt * 32 + akc);
        const uint4 b0 = bs[0], b1v = bs[1];

        __syncthreads();
        *(uint4*)(s_a + arow * 40 + akc)     = a0;
        *(uint4*)(s_a + arow * 40 + akc + 8) = a1;
        *(uint4*)(s_b + arow * 40 + akc)     = b0;
        *(uint4*)(s_b + arow * 40 + akc + 8) = b1v;
        __syncthreads();

        f16x8 af[4];
        #pragma unroll
        for (int im = 0; im < 4; ++im)
            af[im] = *(const f16x8*)(s_a + (wm * 64 + im * 16 + l15) * 40 + q * 8);
        #pragma unroll
        for (int in_ = 0; in_ < 4; ++in_) {
            const f16x8 bf = *(const f16x8*)(s_b + (wn * 64 + in_ * 16 + l15) * 40 + q * 8);
            #pragma unroll
            for (int im = 0; im < 4; ++im)
                acc[im][in_] = __builtin_amdgcn_mfma_f32_16x16x32_f16(af[im], bf, acc[im][in_], 0, 0, 0);
        }
    }

    #pragma unroll
    for (int im = 0; im < 4; ++im)
        #pragma unroll
        for (int in_ = 0; in_ < 4; ++in_)
            #pragma unroll
            for (int r = 0; r < 4; ++r) {
                const int m = m0 + wm * 64 + im * 16 + q * 4 + r;
                const int n = wn * 64 + in_ * 16 + l15;   // < 128
                float v = acc[im][in_][r] + b2[n];
                v = v > 0.f ? v : 0.f;
                h0buf[(size_t)m * H + n] = (_Float16)v;
            }
}

// ---------------------------------------------------------------------------
// Recurrence: 12 LSTM steps. Block = 512 threads (8 waves), 64 batch rows.
// W_hh fp16 resident in LDS (padded rows: 136 halfs -> conflict-free frags).
// g_base held in registers as MFMA C-init. c in registers, h round-trips LDS.
// gates = g_base + p@Wc.T + h@W_hh.T ; p-term folded into elementwise stage.
// Wave w owns gate columns [w*16, w*16+16) of each of the 4 gate blocks.
// ---------------------------------------------------------------------------
__global__ __launch_bounds__(512, 2) void recur_kernel(
    const float* __restrict__ g_base, const _Float16* __restrict__ h0buf,
    const _Float16* __restrict__ whh, const float* __restrict__ wc,
    const float* __restrict__ whp, const float* __restrict__ bhp,
    const float* __restrict__ lpr, float* __restrict__ out)
{
    __shared__ _Float16 s_whh[512 * 136];   // 139264 B
    __shared__ _Float16 s_h[64 * 136];      //  17408 B
    __shared__ float    s_p[128];
    __shared__ float    s_wc[1024];
    __shared__ float    s_whp[256];
    __shared__ float    s_bhp[2];

    const int tid = threadIdx.x;
    const int m0  = blockIdx.x * 64;
    const int lane = tid & 63, w = tid >> 6;      // w 0..7
    const int l15 = lane & 15, q = lane >> 4;

    // ---- stage LDS ----
    #pragma unroll
    for (int i = 0; i < 16; ++i) {
        const int cid = tid + i * 512;            // 0..8191 16B chunks
        const int row = cid >> 4, ch = cid & 15;
        *(uint4*)(s_whh + row * 136 + ch * 8) = *(const uint4*)(whh + row * H + ch * 8);
    }
    if (tid < 256) *(float4*)(s_wc + tid * 4)  = *(const float4*)(wc + tid * 4);
    if (tid < 64)  *(float4*)(s_whp + tid * 4) = *(const float4*)(whp + tid * 4);
    if (tid < 2)   s_bhp[tid] = bhp[tid];
    if (tid < 128) s_p[tid] = lpr[(size_t)m0 * 2 + tid];
    {
        const int row = tid >> 3, ch = tid & 7;   // 64 rows x 8 chunks of 16 halfs
        *(uint4*)(s_h + row * 136 + ch * 16)     = *(const uint4*)(h0buf + (size_t)(m0 + row) * H + ch * 16);
        *(uint4*)(s_h + row * 136 + ch * 16 + 8) = *(const uint4*)(h0buf + (size_t)(m0 + row) * H + ch * 16 + 8);
    }

    // ---- g_base -> registers (C-fragment layout) ----
    f32x4 gb[4][4];   // [im][gate]
    #pragma unroll
    for (int im = 0; im < 4; ++im)
        #pragma unroll
        for (int g = 0; g < 4; ++g)
            #pragma unroll
            for (int r = 0; r < 4; ++r)
                gb[im][g][r] = g_base[(size_t)(m0 + im * 16 + q * 4 + r) * NG + g * H + w * 16 + l15];

    f32x4 cst[4] = {};   // cell state, [im]

    __syncthreads();

    float wc0[4], wc1[4];
    #pragma unroll
    for (int g = 0; g < 4; ++g) {
        const int n = g * H + w * 16 + l15;
        wc0[g] = s_wc[n * 2];
        wc1[g] = s_wc[n * 2 + 1];
    }

    for (int t = 0; t < SEQLEN; ++t) {
        // ---- gates = gb + h @ W_hh.T  (MFMA, C-init = gb) ----
        f32x4 acc[4][4];
        #pragma unroll
        for (int kt = 0; kt < 4; ++kt) {
            f16x8 af[4];
            #pragma unroll
            for (int im = 0; im < 4; ++im)
                af[im] = *(const f16x8*)(s_h + (im * 16 + l15) * 136 + kt * 32 + q * 8);
            #pragma unroll
            for (int g = 0; g < 4; ++g) {
                const f16x8 bf = *(const f16x8*)(s_whh + (g * H + w * 16 + l15) * 136 + kt * 32 + q * 8);
                #pragma unroll
                for (int im = 0; im < 4; ++im)
                    acc[im][g] = __builtin_amdgcn_mfma_f32_16x16x32_f16(
                        af[im], bf, (kt == 0) ? gb[im][g] : acc[im][g], 0, 0, 0);
            }
        }
        __syncthreads();   // all waves done reading s_h

        // ---- elementwise LSTM cell (+ p-term), write new h ----
        #pragma unroll
        for (int im = 0; im < 4; ++im) {
            #pragma unroll
            for (int r = 0; r < 4; ++r) {
                const int mrow = im * 16 + q * 4 + r;
                const float pa = s_p[mrow * 2], pb = s_p[mrow * 2 + 1];
                const float gi = acc[im][0][r] + pa * wc0[0] + pb * wc1[0];
                const float gf = acc[im][1][r] + pa * wc0[1] + pb * wc1[1];
                const float gg = acc[im][2][r] + pa * wc0[2] + pb * wc1[2];
                const float go = acc[im][3][r] + pa * wc0[3] + pb * wc1[3];
                const float cc = sigf(gf) * cst[im][r] + sigf(gi) * tanhfast(gg);
                cst[im][r] = cc;
                const float hh = sigf(go) * tanhfast(cc);
                s_h[mrow * 136 + w * 16 + l15] = (_Float16)hh;
            }
        }
        __syncthreads();   // new h visible

        // ---- rel_pos = h @ W_hp.T + b_hp ; update p; emit output ----
        {
            const int part = tid & 3;          // k-quarter
            const int j    = (tid >> 2) & 1;   // output col
            const int row  = tid >> 3;         // 0..63
            float s = 0.f;
            #pragma unroll
            for (int u = 0; u < 4; ++u) {
                const f16x8 hv = *(const f16x8*)(s_h + row * 136 + part * 32 + u * 8);
                const float4* wp = (const float4*)(s_whp + j * H + part * 32 + u * 8);
                const float4 w0 = wp[0], w1 = wp[1];
                s += (float)hv[0] * w0.x + (float)hv[1] * w0.y + (float)hv[2] * w0.z + (float)hv[3] * w0.w
                   + (float)hv[4] * w1.x + (float)hv[5] * w1.y + (float)hv[6] * w1.z + (float)hv[7] * w1.w;
            }
            s += __shfl_down(s, 2, 64);
            s += __shfl_down(s, 1, 64);
            if (part == 0) {
                s += s_bhp[j];
                s_p[row * 2 + j] = s;
                out[(size_t)t * (BATCH * 2) + (size_t)(m0 + row) * 2 + j] = s;
            }
        }
        __syncthreads();   // p/out done, s_h safe to rebuild next step
    }
}

// ---------------------------------------------------------------------------
extern "C" void kernel_launch(void* const* d_in, const int* in_sizes, int n_in,
                              void* d_out, int out_size, void* d_ws, size_t ws_size,
                              hipStream_t stream)
{
    const float* last_pos_rel = (const float*)d_in[1];
    const float* enc          = (const float*)d_in[2];
    const float* zin          = (const float*)d_in[3];
    const float* W_ih         = (const float*)d_in[5];
    const float* W_hh         = (const float*)d_in[6];
    const float* b_ih         = (const float*)d_in[7];
    const float* b_hh         = (const float*)d_in[8];
    const float* W1           = (const float*)d_in[9];
    const float* b1           = (const float*)d_in[10];
    const float* W2           = (const float*)d_in[11];
    const float* b2           = (const float*)d_in[12];
    const float* W_sp         = (const float*)d_in[13];
    const float* b_sp         = (const float*)d_in[14];
    const float* W_hp         = (const float*)d_in[15];
    const float* b_hp         = (const float*)d_in[16];
    float* out = (float*)d_out;

    char* ws = (char*)d_ws;
    _Float16* wcat  = (_Float16*)(ws + WCAT_OFF);
    _Float16* w2h   = (_Float16*)(ws + W2H_OFF);
    _Float16* whh   = (_Float16*)(ws + WHH_OFF);
    float*    wc    = (float*)(ws + WC_OFF);
    float*    bias2 = (float*)(ws + BIAS2_OFF);
    _Float16* t1    = (_Float16*)(ws + T1_OFF);
    float*    gbase = (float*)(ws + GB_OFF);
    _Float16* h0b   = (_Float16*)(ws + H0_OFF);

    prep_kernel<<<dim3(2182), 256, 0, stream>>>(W_ih, W_hh, b_ih, b_hh, W1, W2, W_sp, b_sp,
                                                wcat, w2h, whh, wc, bias2);
    gemm1_kernel<<<dim3(12, 256), 256, 0, stream>>>(enc, zin, wcat, b1, bias2, t1, gbase);
    gemm2_kernel<<<dim3(256), 256, 0, stream>>>(t1, w2h, b2, h0b);
    recur_kernel<<<dim3(512), 512, 0, stream>>>(gbase, h0b, whh, wc, W_hp, b_hp,
                                                last_pos_rel, out);
}

// Round 3
// 620.764 us; speedup vs baseline: 1.0286x; 1.0286x over previous
//
#include <hip/hip_runtime.h>

// ---------- problem constants ----------
#define BATCH   32768
#define SEQLEN  12
#define EMB     64
#define H       128
#define MLP     1024
#define Z       32
#define ZX      1056      // MLP + Z
#define NG      512       // 4*H gates

typedef _Float16 f16x8 __attribute__((ext_vector_type(8)));
typedef float    f32x4 __attribute__((ext_vector_type(4)));

// ---------- workspace layout (bytes), total 146,249,728 ----------
#define WCAT_OFF   0u          // 1536*1056*2 = 3,244,032
#define W2H_OFF    3244032u    // 128*1024*2  =   262,144
#define WHHF_OFF   3506176u    // 512*128*2   =   131,072
#define WC_OFF     3637248u    // 512*2*4     =     4,096
#define BIAS2_OFF  3641344u    // 512*4       =     2,048
#define T1_OFF     3643392u    // 32768*1024*2 = 67,108,864
#define GP_OFF     70752256u   // 8192*512*4*4 = 67,108,864 (permuted g_base)
#define H0_OFF     137861120u  // 32768*128*2  =  8,388,608

__device__ __forceinline__ float sigf(float x) {
    return __builtin_amdgcn_rcpf(1.0f + __expf(-x));
}
__device__ __forceinline__ float tanhfast(float x) {
    return 2.0f * __builtin_amdgcn_rcpf(1.0f + __expf(-2.0f * x)) - 1.0f;
}

// async global->LDS, 16B per lane. LDS dest = wave-uniform base + lane*16.
__device__ __forceinline__ void gload16(const void* g, void* l) {
    __builtin_amdgcn_global_load_lds(
        (const __attribute__((address_space(1))) unsigned int*)(unsigned long long)(uintptr_t)g,
        (__attribute__((address_space(3))) unsigned int*)(unsigned int)(uintptr_t)l,
        16, 0, 0);
}

// ---------------------------------------------------------------------------
// prep: pack weights fp16, fold biases, fold rel_pos feedback into W_hh.
//   wcat[n][k]: n<1024 W1 row n; n>=1024 W_ih row n-1024 cols 0..1055
//   w2h = fp16(W2); whhf = fp16(W_hh + Wc@W_hp) where Wc = W_emb@W_sp (512x2)
//   wc[n][j] = Wc; bias2[n] = b_ih + b_hh + W_emb@b_sp
// ---------------------------------------------------------------------------
__global__ __launch_bounds__(256) void prep_kernel(
    const float* __restrict__ W_ih, const float* __restrict__ W_hh_in,
    const float* __restrict__ b_ih, const float* __restrict__ b_hh,
    const float* __restrict__ W1,   const float* __restrict__ W2,
    const float* __restrict__ W_sp, const float* __restrict__ b_sp,
    const float* __restrict__ W_hp,
    _Float16* __restrict__ wcat, _Float16* __restrict__ w2h,
    _Float16* __restrict__ whhf, float* __restrict__ wc, float* __restrict__ bias2)
{
    const int bid = blockIdx.x;
    const int tid = threadIdx.x;
    if (bid < 1536) {
        const float* src = (bid < 1024) ? (W1 + (size_t)bid * ZX)
                                        : (W_ih + (size_t)(bid - 1024) * 1120);
        _Float16* dst = wcat + (size_t)bid * ZX;
        for (int k = tid; k < ZX; k += 256) dst[k] = (_Float16)src[k];
    } else if (bid < 1664) {
        const int n = bid - 1536;
        for (int k = tid; k < MLP; k += 256)
            w2h[n * MLP + k] = (_Float16)W2[n * MLP + k];
    } else if (bid < 1920) {
        // whhf: 2 rows per block
        const int n = (bid - 1664) * 2 + (tid >> 7);
        const int k = tid & 127;
        float wc0 = 0.f, wc1 = 0.f;
        for (int e = 0; e < EMB; ++e) {
            const float we = W_ih[(size_t)n * 1120 + ZX + e];
            wc0 += we * W_sp[e * 2];
            wc1 += we * W_sp[e * 2 + 1];
        }
        whhf[n * H + k] = (_Float16)(W_hh_in[n * H + k] + wc0 * W_hp[k] + wc1 * W_hp[H + k]);
    } else {
        const int t = (bid - 1920) * 256 + tid;
        if (t < 1024) {
            const int n = t >> 1, j = t & 1;
            float s = 0.f;
            for (int e = 0; e < EMB; ++e)
                s += W_ih[(size_t)n * 1120 + ZX + e] * W_sp[e * 2 + j];
            wc[t] = s;
        } else if (t < 1536) {
            const int n = t - 1024;
            float s = b_ih[n] + b_hh[n];
            for (int e = 0; e < EMB; ++e)
                s += W_ih[(size_t)n * 1120 + ZX + e] * b_sp[e];
            bias2[n] = s;
        }
    }
}

// ---------------------------------------------------------------------------
// GEMM1: C[32768,1536] = zx[.,1056] @ wcat.T ; zx = [enc|z] fp32 read direct.
// m97 structure: global_load_lds(16B) for A (fp32, cvt at frag read) and B.
// LDS chunk-XOR swizzle -> 2-way (free) banks on ds_read_b128.
// XCD swizzle: 12 bn-blocks of one m-tile run consecutively on one XCD.
//   n<1024 : t1 = fp16(relu(C+b1))
//   n>=1024: gperm[((m>>2)*512+n)*4 + (m&3)] = C + bias2   (float4-readable)
// ---------------------------------------------------------------------------
__global__ __launch_bounds__(256) void gemm1_kernel(
    const float* __restrict__ enc, const float* __restrict__ zin,
    const _Float16* __restrict__ wcat,
    const float* __restrict__ bias1, const float* __restrict__ bias2g,
    _Float16* __restrict__ t1, float* __restrict__ gperm)
{
    __shared__ float    s_a[128 * 32];   // 16 KB, fp32 A tile (swizzled chunks)
    __shared__ _Float16 s_b[128 * 32];   //  8 KB, fp16 B tile (swizzled chunks)

    const int tid = threadIdx.x;
    const int b = blockIdx.x;
    const int x = b & 7, s = b >> 3;        // XCD, sequence within XCD
    const int mt = x * 32 + s / 12;         // m-tile 0..255
    const int bn = s % 12;                  // n-tile 0..11
    const int m0 = mt * 128;

    const int lane = tid & 63, wv = tid >> 6;
    const int wm = wv >> 1, wn = wv & 1;
    const int l15 = lane & 15, q = lane >> 4;

    // A staging: row rA=i*32+(tid>>3), actual chunk cA=(tid&7)^((tid>>3)&7)
    const int rowA = tid >> 3;
    const int chA  = (tid & 7) ^ ((tid >> 3) & 7);
    // B staging: row rB=i*64+(tid>>2), actual chunk cB=(tid&3)^((tid>>3)&3)
    const int rowB = tid >> 2;
    const int chB  = (tid & 3) ^ ((tid >> 3) & 3);

    // frag-read swizzled chunk indices (per-lane constants)
    const int ca0 = (2 * q) ^ (l15 & 7);          // A chunk for low float4
    const int cb  = q ^ ((l15 >> 1) & 3);         // B chunk

    f32x4 acc[4][4] = {};

    for (int kt = 0; kt < 33; ++kt) {
        const float* abase;
        size_t astride;
        if (kt < 32) { abase = enc + (size_t)m0 * MLP + kt * 32; astride = MLP; }
        else         { abase = zin + (size_t)m0 * Z;             astride = Z;   }

        __syncthreads();   // previous tile fully consumed
        #pragma unroll
        for (int i = 0; i < 4; ++i)
            gload16(abase + (size_t)(i * 32 + rowA) * astride + chA * 4,
                    s_a + i * 1024 + wv * 256);
        #pragma unroll
        for (int i = 0; i < 2; ++i)
            gload16(wcat + (size_t)(bn * 128 + i * 64 + rowB) * ZX + kt * 32 + chB * 8,
                    s_b + i * 2048 + wv * 512);
        __syncthreads();   // drains vmcnt(0): tiles resident

        f16x8 af[4];
        #pragma unroll
        for (int im = 0; im < 4; ++im) {
            const float* ap = s_a + (wm * 64 + im * 16 + l15) * 32;
            const float4 f0 = *(const float4*)(ap + ca0 * 4);
            const float4 f1 = *(const float4*)(ap + (ca0 ^ 1) * 4);
            af[im] = f16x8{(_Float16)f0.x, (_Float16)f0.y, (_Float16)f0.z, (_Float16)f0.w,
                           (_Float16)f1.x, (_Float16)f1.y, (_Float16)f1.z, (_Float16)f1.w};
        }
        #pragma unroll
        for (int in_ = 0; in_ < 4; ++in_) {
            const f16x8 bf = *(const f16x8*)(s_b + (wn * 64 + in_ * 16 + l15) * 32 + cb * 8);
            #pragma unroll
            for (int im = 0; im < 4; ++im)
                acc[im][in_] = __builtin_amdgcn_mfma_f32_16x16x32_f16(af[im], bf, acc[im][in_], 0, 0, 0);
        }
    }

    // epilogue (C layout: col = lane&15, row = (lane>>4)*4 + reg)
    if (bn < 8) {
        #pragma unroll
        for (int im = 0; im < 4; ++im)
            #pragma unroll
            for (int in_ = 0; in_ < 4; ++in_) {
                const int n = bn * 128 + wn * 64 + in_ * 16 + l15;
                const float bb = bias1[n];
                #pragma unroll
                for (int r = 0; r < 4; ++r) {
                    const int m = m0 + wm * 64 + im * 16 + q * 4 + r;
                    float v = acc[im][in_][r] + bb;
                    v = v > 0.f ? v : 0.f;
                    t1[(size_t)m * MLP + n] = (_Float16)v;
                }
            }
    } else {
        #pragma unroll
        for (int im = 0; im < 4; ++im)
            #pragma unroll
            for (int in_ = 0; in_ < 4; ++in_) {
                const int n = (bn - 8) * 128 + wn * 64 + in_ * 16 + l15;
                const float bb = bias2g[n];
                const int m4 = (m0 + wm * 64 + im * 16 + q * 4) >> 2;
                float4 v;
                v.x = acc[im][in_][0] + bb;
                v.y = acc[im][in_][1] + bb;
                v.z = acc[im][in_][2] + bb;
                v.w = acc[im][in_][3] + bb;
                *(float4*)(gperm + ((size_t)m4 * NG + n) * 4) = v;
            }
    }
}

// ---------------------------------------------------------------------------
// GEMM2: h0[32768,128] = fp16(relu(t1[.,1024] @ w2h.T + b2)); same structure.
// ---------------------------------------------------------------------------
__global__ __launch_bounds__(256) void gemm2_kernel(
    const _Float16* __restrict__ t1, const _Float16* __restrict__ w2h,
    const float* __restrict__ b2, _Float16* __restrict__ h0buf)
{
    __shared__ _Float16 s_a[128 * 32];
    __shared__ _Float16 s_b[128 * 32];

    const int tid = threadIdx.x;
    const int m0  = blockIdx.x * 128;
    const int lane = tid & 63, wv = tid >> 6;
    const int wm = wv >> 1, wn = wv & 1;
    const int l15 = lane & 15, q = lane >> 4;

    const int rowB = tid >> 2;
    const int chB  = (tid & 3) ^ ((tid >> 3) & 3);
    const int cb   = q ^ ((l15 >> 1) & 3);

    f32x4 acc[4][4] = {};

    for (int kt = 0; kt < 32; ++kt) {
        __syncthreads();
        #pragma unroll
        for (int i = 0; i < 2; ++i)
            gload16(t1 + (size_t)(m0 + i * 64 + rowB) * MLP + kt * 32 + chB * 8,
                    s_a + i * 2048 + wv * 512);
        #pragma unroll
        for (int i = 0; i < 2; ++i)
            gload16(w2h + (size_t)(i * 64 + rowB) * MLP + kt * 32 + chB * 8,
                    s_b + i * 2048 + wv * 512);
        __syncthreads();

        f16x8 af[4];
        #pragma unroll
        for (int im = 0; im < 4; ++im)
            af[im] = *(const f16x8*)(s_a + (wm * 64 + im * 16 + l15) * 32 + cb * 8);
        #pragma unroll
        for (int in_ = 0; in_ < 4; ++in_) {
            const f16x8 bf = *(const f16x8*)(s_b + (wn * 64 + in_ * 16 + l15) * 32 + cb * 8);
            #pragma unroll
            for (int im = 0; im < 4; ++im)
                acc[im][in_] = __builtin_amdgcn_mfma_f32_16x16x32_f16(af[im], bf, acc[im][in_], 0, 0, 0);
        }
    }

    #pragma unroll
    for (int im = 0; im < 4; ++im)
        #pragma unroll
        for (int in_ = 0; in_ < 4; ++in_) {
            const int n = wn * 64 + in_ * 16 + l15;   // < 128
            const float bb = b2[n];
            #pragma unroll
            for (int r = 0; r < 4; ++r) {
                const int m = m0 + wm * 64 + im * 16 + q * 4 + r;
                float v = acc[im][in_][r] + bb;
                v = v > 0.f ? v : 0.f;
                h0buf[(size_t)m * H + n] = (_Float16)v;
            }
        }
}

// ---------------------------------------------------------------------------
// Recurrence, rel_pos feedback folded into whhf. 512 thr / 64 rows / block.
// gates_t = gb + h_{t-1} @ whhf.T
//   t=0 : whhf adds spurious q0@Wc.T (q0 = h_init@W_hp.T); corrected by
//         folding (p_{-1} - q0)@Wc.T into gb for step 0.
//   t>=1: exact fold; constant cg = Wc@b_hp.
// 2 barriers/step; rel_pos output off the critical path.
// ---------------------------------------------------------------------------
__global__ __launch_bounds__(512) void recur_kernel(
    const float* __restrict__ gperm, const _Float16* __restrict__ h0buf,
    const _Float16* __restrict__ whhf, const float* __restrict__ wc,
    const float* __restrict__ whp, const float* __restrict__ bhp,
    const float* __restrict__ lpr, float* __restrict__ out)
{
    __shared__ _Float16 s_whh[512 * 136];   // 139264 B
    __shared__ _Float16 s_h[64 * 136];      //  17408 B
    __shared__ float    s_p[128];           // p_{-1}, then p_{-1} - q0
    __shared__ float    s_wc[1024];
    __shared__ float    s_whp[256];
    __shared__ float    s_bhp[2];

    const int tid = threadIdx.x;
    const int m0  = blockIdx.x * 64;
    const int lane = tid & 63, w = tid >> 6;      // w 0..7
    const int l15 = lane & 15, q = lane >> 4;

    // ---- stage LDS ----
    #pragma unroll
    for (int i = 0; i < 16; ++i) {
        const int cid = tid + i * 512;
        const int row = cid >> 4, ch = cid & 15;
        *(uint4*)(s_whh + row * 136 + ch * 8) = *(const uint4*)(whhf + row * H + ch * 8);
    }
    if (tid < 256) *(float4*)(s_wc + tid * 4)  = *(const float4*)(wc + tid * 4);
    if (tid < 64)  *(float4*)(s_whp + tid * 4) = *(const float4*)(whp + tid * 4);
    if (tid < 2)   s_bhp[tid] = bhp[tid];
    if (tid < 128) s_p[tid] = lpr[(size_t)m0 * 2 + tid];
    {
        const int row = tid >> 3, ch = tid & 7;
        *(uint4*)(s_h + row * 136 + ch * 16)     = *(const uint4*)(h0buf + (size_t)(m0 + row) * H + ch * 16);
        *(uint4*)(s_h + row * 136 + ch * 16 + 8) = *(const uint4*)(h0buf + (size_t)(m0 + row) * H + ch * 16 + 8);
    }

    // ---- g_base -> registers, coalesced float4 from permuted layout ----
    f32x4 gb[4][4];   // [im][gate]
    #pragma unroll
    for (int im = 0; im < 4; ++im) {
        const int m4 = (m0 >> 2) + im * 4 + q;
        #pragma unroll
        for (int g = 0; g < 4; ++g) {
            const float4 v = *(const float4*)(gperm + ((size_t)m4 * NG + g * H + w * 16 + l15) * 4);
            gb[im][g] = f32x4{v.x, v.y, v.z, v.w};
        }
    }

    f32x4 cst[4] = {};

    __syncthreads();

    // ---- q0 = h_init @ W_hp.T (no bias); s_p <- p_{-1} - q0 ----
    {
        const int part = tid & 3;
        const int j    = (tid >> 2) & 1;
        const int row  = tid >> 3;
        float sum = 0.f;
        #pragma unroll
        for (int u = 0; u < 4; ++u) {
            const f16x8 hv = *(const f16x8*)(s_h + row * 136 + part * 32 + u * 8);
            const float4* wp = (const float4*)(s_whp + j * H + part * 32 + u * 8);
            const float4 w0 = wp[0], w1 = wp[1];
            sum += (float)hv[0] * w0.x + (float)hv[1] * w0.y + (float)hv[2] * w0.z + (float)hv[3] * w0.w
                 + (float)hv[4] * w1.x + (float)hv[5] * w1.y + (float)hv[6] * w1.z + (float)hv[7] * w1.w;
        }
        sum += __shfl_down(sum, 2, 64);
        sum += __shfl_down(sum, 1, 64);
        if (part == 0) s_p[row * 2 + j] -= sum;
    }
    __syncthreads();

    float wc0[4], wc1[4], cg[4];
    #pragma unroll
    for (int g = 0; g < 4; ++g) {
        const int n = g * H + w * 16 + l15;
        wc0[g] = s_wc[n * 2];
        wc1[g] = s_wc[n * 2 + 1];
        cg[g]  = wc0[g] * s_bhp[0] + wc1[g] * s_bhp[1];
    }
    // fold step-0 term (p_{-1} - q0)@Wc.T into gb
    #pragma unroll
    for (int im = 0; im < 4; ++im)
        #pragma unroll
        for (int r = 0; r < 4; ++r) {
            const int mrow = im * 16 + q * 4 + r;
            const float pa = s_p[mrow * 2], pb = s_p[mrow * 2 + 1];
            #pragma unroll
            for (int g = 0; g < 4; ++g)
                gb[im][g][r] += pa * wc0[g] + pb * wc1[g];
        }

    for (int t = 0; t < SEQLEN; ++t) {
        // ---- gates = gb + h @ whhf.T ----
        f32x4 acc[4][4];
        #pragma unroll
        for (int kt = 0; kt < 4; ++kt) {
            f16x8 af[4];
            #pragma unroll
            for (int im = 0; im < 4; ++im)
                af[im] = *(const f16x8*)(s_h + (im * 16 + l15) * 136 + kt * 32 + q * 8);
            #pragma unroll
            for (int g = 0; g < 4; ++g) {
                const f16x8 bf = *(const f16x8*)(s_whh + (g * H + w * 16 + l15) * 136 + kt * 32 + q * 8);
                #pragma unroll
                for (int im = 0; im < 4; ++im)
                    acc[im][g] = __builtin_amdgcn_mfma_f32_16x16x32_f16(
                        af[im], bf, (kt == 0) ? gb[im][g] : acc[im][g], 0, 0, 0);
            }
        }
        __syncthreads();   // all waves done reading s_h

        // ---- LSTM cell elementwise, write new h ----
        #pragma unroll
        for (int im = 0; im < 4; ++im) {
            #pragma unroll
            for (int r = 0; r < 4; ++r) {
                const int mrow = im * 16 + q * 4 + r;
                const float cc = sigf(acc[im][1][r]) * cst[im][r]
                               + sigf(acc[im][0][r]) * tanhfast(acc[im][2][r]);
                cst[im][r] = cc;
                const float hh = sigf(acc[im][3][r]) * tanhfast(cc);
                s_h[mrow * 136 + w * 16 + l15] = (_Float16)hh;
            }
        }
        if (t == 0) {
            // switch gb from step-0 fold to steady-state constant cg
            #pragma unroll
            for (int im = 0; im < 4; ++im)
                #pragma unroll
                for (int r = 0; r < 4; ++r) {
                    const int mrow = im * 16 + q * 4 + r;
                    const float pa = s_p[mrow * 2], pb = s_p[mrow * 2 + 1];
                    #pragma unroll
                    for (int g = 0; g < 4; ++g)
                        gb[im][g][r] += cg[g] - (pa * wc0[g] + pb * wc1[g]);
                }
        }
        __syncthreads();   // new h visible

        // ---- rel_pos = h @ W_hp.T + b_hp ; output only (not fed back) ----
        {
            const int part = tid & 3;
            const int j    = (tid >> 2) & 1;
            const int row  = tid >> 3;
            float sum = 0.f;
            #pragma unroll
            for (int u = 0; u < 4; ++u) {
                const f16x8 hv = *(const f16x8*)(s_h + row * 136 + part * 32 + u * 8);
                const float4* wp = (const float4*)(s_whp + j * H + part * 32 + u * 8);
                const float4 w0 = wp[0], w1 = wp[1];
                sum += (float)hv[0] * w0.x + (float)hv[1] * w0.y + (float)hv[2] * w0.z + (float)hv[3] * w0.w
                     + (float)hv[4] * w1.x + (float)hv[5] * w1.y + (float)hv[6] * w1.z + (float)hv[7] * w1.w;
            }
            sum += __shfl_down(sum, 2, 64);
            sum += __shfl_down(sum, 1, 64);
            if (part == 0)
                out[(size_t)t * (BATCH * 2) + (size_t)(m0 + row) * 2 + j] = sum + s_bhp[j];
        }
        // next MFMA reads s_h only; the next post-MFMA barrier orders these
        // reads against the following s_h overwrite.
    }
}

// ---------------------------------------------------------------------------
extern "C" void kernel_launch(void* const* d_in, const int* in_sizes, int n_in,
                              void* d_out, int out_size, void* d_ws, size_t ws_size,
                              hipStream_t stream)
{
    const float* last_pos_rel = (const float*)d_in[1];
    const float* enc          = (const float*)d_in[2];
    const float* zin          = (const float*)d_in[3];
    const float* W_ih         = (const float*)d_in[5];
    const float* W_hh         = (const float*)d_in[6];
    const float* b_ih         = (const float*)d_in[7];
    const float* b_hh         = (const float*)d_in[8];
    const float* W1           = (const float*)d_in[9];
    const float* b1           = (const float*)d_in[10];
    const float* W2           = (const float*)d_in[11];
    const float* b2           = (const float*)d_in[12];
    const float* W_sp         = (const float*)d_in[13];
    const float* b_sp         = (const float*)d_in[14];
    const float* W_hp         = (const float*)d_in[15];
    const float* b_hp         = (const float*)d_in[16];
    float* out = (float*)d_out;

    char* ws = (char*)d_ws;
    _Float16* wcat  = (_Float16*)(ws + WCAT_OFF);
    _Float16* w2h   = (_Float16*)(ws + W2H_OFF);
    _Float16* whhf  = (_Float16*)(ws + WHHF_OFF);
    float*    wc    = (float*)(ws + WC_OFF);
    float*    bias2 = (float*)(ws + BIAS2_OFF);
    _Float16* t1    = (_Float16*)(ws + T1_OFF);
    float*    gperm = (float*)(ws + GP_OFF);
    _Float16* h0b   = (_Float16*)(ws + H0_OFF);

    prep_kernel<<<dim3(1926), 256, 0, stream>>>(W_ih, W_hh, b_ih, b_hh, W1, W2, W_sp, b_sp,
                                                W_hp, wcat, w2h, whhf, wc, bias2);
    gemm1_kernel<<<dim3(3072), 256, 0, stream>>>(enc, zin, wcat, b1, bias2, t1, gperm);
    gemm2_kernel<<<dim3(256), 256, 0, stream>>>(t1, w2h, b2, h0b);
    recur_kernel<<<dim3(512), 512, 0, stream>>>(gperm, h0b, whhf, wc, W_hp, b_hp,
                                                last_pos_rel, out);
}

// Round 4
// 530.586 us; speedup vs baseline: 1.2035x; 1.1700x over previous
//
#include <hip/hip_runtime.h>

// ---------- problem constants ----------
#define BATCH   32768
#define SEQLEN  12
#define EMB     64
#define H       128
#define MLP     1024
#define Z       32
#define ZX      1056      // MLP + Z
#define KP      1088      // ZX padded to 17*64 (big path)
#define NG      512       // 4*H gates

typedef _Float16 f16x8 __attribute__((ext_vector_type(8)));
typedef float    f32x4 __attribute__((ext_vector_type(4)));

// ---------- workspace layouts ----------
// small path (ws < 217,651,200): round-3 layout, total 146,249,728
#define S_WCAT_OFF   0u
#define S_W2H_OFF    3244032u
#define S_WHHF_OFF   3506176u
#define S_WC_OFF     3637248u
#define S_BIAS2_OFF  3641344u
#define S_T1_OFF     3643392u
#define S_GP_OFF     70752256u
#define S_H0_OFF     137861120u
// big path: wcat stride 1088 + zx16 buffer, total 217,651,200
#define B_WCAT_OFF   0u           // 1536*1088*2 = 3,342,336
#define B_W2H_OFF    3342336u
#define B_WHHF_OFF   3604480u
#define B_WC_OFF     3735552u
#define B_BIAS2_OFF  3739648u
#define B_T1_OFF     3741696u
#define B_GP_OFF     70850560u
#define B_H0_OFF     137959424u
#define B_ZX16_OFF   146348032u
#define B_TOTAL      217651200ull

__device__ __forceinline__ float sigf(float x) {
    return __builtin_amdgcn_rcpf(1.0f + __expf(-x));
}
__device__ __forceinline__ float tanhfast(float x) {
    return 2.0f * __builtin_amdgcn_rcpf(1.0f + __expf(-2.0f * x)) - 1.0f;
}

// async global->LDS, 16B per lane. LDS dest = wave-uniform base + lane*16.
__device__ __forceinline__ void gload16(const void* g, void* l) {
    __builtin_amdgcn_global_load_lds(
        (const __attribute__((address_space(1))) unsigned int*)(unsigned long long)(uintptr_t)g,
        (__attribute__((address_space(3))) unsigned int*)(unsigned int)(uintptr_t)l,
        16, 0, 0);
}

// ---------------------------------------------------------------------------
// prep: pack weights fp16 (wcat stride = cs, zero-padded past 1056),
// fold biases, fold rel_pos feedback into W_hh.
// ---------------------------------------------------------------------------
__global__ __launch_bounds__(256) void prep_kernel(
    const float* __restrict__ W_ih, const float* __restrict__ W_hh_in,
    const float* __restrict__ b_ih, const float* __restrict__ b_hh,
    const float* __restrict__ W1,   const float* __restrict__ W2,
    const float* __restrict__ W_sp, const float* __restrict__ b_sp,
    const float* __restrict__ W_hp, int cs,
    _Float16* __restrict__ wcat, _Float16* __restrict__ w2h,
    _Float16* __restrict__ whhf, float* __restrict__ wc, float* __restrict__ bias2)
{
    const int bid = blockIdx.x;
    const int tid = threadIdx.x;
    if (bid < 1536) {
        const float* src = (bid < 1024) ? (W1 + (size_t)bid * ZX)
                                        : (W_ih + (size_t)(bid - 1024) * 1120);
        _Float16* dst = wcat + (size_t)bid * cs;
        for (int k = tid; k < cs; k += 256)
            dst[k] = (k < ZX) ? (_Float16)src[k] : (_Float16)0.f;
    } else if (bid < 1664) {
        const int n = bid - 1536;
        for (int k = tid; k < MLP; k += 256)
            w2h[n * MLP + k] = (_Float16)W2[n * MLP + k];
    } else if (bid < 1920) {
        const int n = (bid - 1664) * 2 + (tid >> 7);
        const int k = tid & 127;
        float wc0 = 0.f, wc1 = 0.f;
        for (int e = 0; e < EMB; ++e) {
            const float we = W_ih[(size_t)n * 1120 + ZX + e];
            wc0 += we * W_sp[e * 2];
            wc1 += we * W_sp[e * 2 + 1];
        }
        whhf[n * H + k] = (_Float16)(W_hh_in[n * H + k] + wc0 * W_hp[k] + wc1 * W_hp[H + k]);
    } else {
        const int t = (bid - 1920) * 256 + tid;
        if (t < 1024) {
            const int n = t >> 1, j = t & 1;
            float s = 0.f;
            for (int e = 0; e < EMB; ++e)
                s += W_ih[(size_t)n * 1120 + ZX + e] * W_sp[e * 2 + j];
            wc[t] = s;
        } else if (t < 1536) {
            const int n = t - 1024;
            float s = b_ih[n] + b_hh[n];
            for (int e = 0; e < EMB; ++e)
                s += W_ih[(size_t)n * 1120 + ZX + e] * b_sp[e];
            bias2[n] = s;
        }
    }
}

// ---------------------------------------------------------------------------
// zxcast (big path): zx16[32768][1088] = fp16([enc | z | zeros])
// 8 halfs per thread; grid = 4456448/256 = 17408 blocks.
// ---------------------------------------------------------------------------
__global__ __launch_bounds__(256) void zxcast_kernel(
    const float* __restrict__ enc, const float* __restrict__ zin,
    _Float16* __restrict__ zx16)
{
    const int gid = blockIdx.x * 256 + threadIdx.x;
    if (gid < 4194304) {                       // enc: 128 chunks/row
        const int row = gid >> 7, cw = gid & 127;
        const float4* s = (const float4*)(enc + (size_t)row * MLP + cw * 8);
        const float4 f0 = s[0], f1 = s[1];
        f16x8 v = {(_Float16)f0.x, (_Float16)f0.y, (_Float16)f0.z, (_Float16)f0.w,
                   (_Float16)f1.x, (_Float16)f1.y, (_Float16)f1.z, (_Float16)f1.w};
        *(f16x8*)(zx16 + (size_t)row * KP + cw * 8) = v;
    } else if (gid < 4325376) {                // z: 4 chunks/row
        const int g2 = gid - 4194304;
        const int row = g2 >> 2, cw = g2 & 3;
        const float4* s = (const float4*)(zin + (size_t)row * Z + cw * 8);
        const float4 f0 = s[0], f1 = s[1];
        f16x8 v = {(_Float16)f0.x, (_Float16)f0.y, (_Float16)f0.z, (_Float16)f0.w,
                   (_Float16)f1.x, (_Float16)f1.y, (_Float16)f1.z, (_Float16)f1.w};
        *(f16x8*)(zx16 + (size_t)row * KP + MLP + cw * 8) = v;
    } else {                                   // pad: 4 chunks/row of zeros
        const int g2 = gid - 4325376;
        const int row = g2 >> 2, cw = g2 & 3;
        f16x8 v = {};
        *(f16x8*)(zx16 + (size_t)row * KP + ZX + cw * 8) = v;
    }
}

// ---------------------------------------------------------------------------
// GEMM1 big path: C[32768,1536] = zx16[.,1088] @ wcat16.T, BK=64, fp16 A.
// 17 k-tiles; per iter: 8 gload16, 16 ds_read_b128, 32 MFMA per wave.
// XOR swizzle (8 chunks/row, pch = c ^ (row&7)) -> 2-way banks (free).
// XCD swizzle unchanged. Epilogue identical to round 3.
// ---------------------------------------------------------------------------
__global__ __launch_bounds__(256) void gemm1_big_kernel(
    const _Float16* __restrict__ zx16, const _Float16* __restrict__ wcat,
    const float* __restrict__ bias1, const float* __restrict__ bias2g,
    _Float16* __restrict__ t1, float* __restrict__ gperm)
{
    __shared__ _Float16 s_a[128 * 64];   // 16 KB
    __shared__ _Float16 s_b[128 * 64];   // 16 KB

    const int tid = threadIdx.x;
    const int b = blockIdx.x;
    const int x = b & 7, s = b >> 3;
    const int mt = x * 32 + s / 12;
    const int bn = s % 12;
    const int m0 = mt * 128;

    const int lane = tid & 63, wv = tid >> 6;
    const int wm = wv >> 1, wn = wv & 1;
    const int l15 = lane & 15, q = lane >> 4;

    // staging: slot P=i*256+tid -> row=P>>3, pch=P&7, logical c=pch^(row&7)
    const int rowS = tid >> 3;
    const int chS  = (tid & 7) ^ ((tid >> 3) & 7);

    f32x4 acc[4][4] = {};

    for (int kt = 0; kt < 17; ++kt) {
        __syncthreads();   // previous tile fully consumed
        #pragma unroll
        for (int i = 0; i < 4; ++i)
            gload16(zx16 + (size_t)(m0 + i * 32 + rowS) * KP + kt * 64 + chS * 8,
                    s_a + i * 2048 + wv * 512);
        #pragma unroll
        for (int i = 0; i < 4; ++i)
            gload16(wcat + (size_t)(bn * 128 + i * 32 + rowS) * KP + kt * 64 + chS * 8,
                    s_b + i * 2048 + wv * 512);
        __syncthreads();   // tiles resident

        #pragma unroll
        for (int kt2 = 0; kt2 < 2; ++kt2) {
            f16x8 af[4];
            #pragma unroll
            for (int im = 0; im < 4; ++im) {
                const int row = wm * 64 + im * 16 + l15;
                const int ph  = (kt2 * 4 + q) ^ (l15 & 7);
                af[im] = *(const f16x8*)(s_a + row * 64 + ph * 8);
            }
            #pragma unroll
            for (int in_ = 0; in_ < 4; ++in_) {
                const int row = wn * 64 + in_ * 16 + l15;
                const int ph  = (kt2 * 4 + q) ^ (l15 & 7);
                const f16x8 bf = *(const f16x8*)(s_b + row * 64 + ph * 8);
                #pragma unroll
                for (int im = 0; im < 4; ++im)
                    acc[im][in_] = __builtin_amdgcn_mfma_f32_16x16x32_f16(af[im], bf, acc[im][in_], 0, 0, 0);
            }
        }
    }

    if (bn < 8) {
        #pragma unroll
        for (int im = 0; im < 4; ++im)
            #pragma unroll
            for (int in_ = 0; in_ < 4; ++in_) {
                const int n = bn * 128 + wn * 64 + in_ * 16 + l15;
                const float bb = bias1[n];
                #pragma unroll
                for (int r = 0; r < 4; ++r) {
                    const int m = m0 + wm * 64 + im * 16 + q * 4 + r;
                    float v = acc[im][in_][r] + bb;
                    v = v > 0.f ? v : 0.f;
                    t1[(size_t)m * MLP + n] = (_Float16)v;
                }
            }
    } else {
        #pragma unroll
        for (int im = 0; im < 4; ++im)
            #pragma unroll
            for (int in_ = 0; in_ < 4; ++in_) {
                const int n = (bn - 8) * 128 + wn * 64 + in_ * 16 + l15;
                const float bb = bias2g[n];
                const int m4 = (m0 + wm * 64 + im * 16 + q * 4) >> 2;
                float4 v;
                v.x = acc[im][in_][0] + bb;
                v.y = acc[im][in_][1] + bb;
                v.z = acc[im][in_][2] + bb;
                v.w = acc[im][in_][3] + bb;
                *(float4*)(gperm + ((size_t)m4 * NG + n) * 4) = v;
            }
    }
}

// ---------------------------------------------------------------------------
// GEMM1 small path: round-3 kernel verbatim (fp32 A, BK=32, stride 1056).
// ---------------------------------------------------------------------------
__global__ __launch_bounds__(256) void gemm1_small_kernel(
    const float* __restrict__ enc, const float* __restrict__ zin,
    const _Float16* __restrict__ wcat,
    const float* __restrict__ bias1, const float* __restrict__ bias2g,
    _Float16* __restrict__ t1, float* __restrict__ gperm)
{
    __shared__ float    s_a[128 * 32];
    __shared__ _Float16 s_b[128 * 32];

    const int tid = threadIdx.x;
    const int b = blockIdx.x;
    const int x = b & 7, s = b >> 3;
    const int mt = x * 32 + s / 12;
    const int bn = s % 12;
    const int m0 = mt * 128;

    const int lane = tid & 63, wv = tid >> 6;
    const int wm = wv >> 1, wn = wv & 1;
    const int l15 = lane & 15, q = lane >> 4;

    const int rowA = tid >> 3;
    const int chA  = (tid & 7) ^ ((tid >> 3) & 7);
    const int rowB = tid >> 2;
    const int chB  = (tid & 3) ^ ((tid >> 3) & 3);

    const int ca0 = (2 * q) ^ (l15 & 7);
    const int cb  = q ^ ((l15 >> 1) & 3);

    f32x4 acc[4][4] = {};

    for (int kt = 0; kt < 33; ++kt) {
        const float* abase;
        size_t astride;
        if (kt < 32) { abase = enc + (size_t)m0 * MLP + kt * 32; astride = MLP; }
        else         { abase = zin + (size_t)m0 * Z;             astride = Z;   }

        __syncthreads();
        #pragma unroll
        for (int i = 0; i < 4; ++i)
            gload16(abase + (size_t)(i * 32 + rowA) * astride + chA * 4,
                    s_a + i * 1024 + wv * 256);
        #pragma unroll
        for (int i = 0; i < 2; ++i)
            gload16(wcat + (size_t)(bn * 128 + i * 64 + rowB) * ZX + kt * 32 + chB * 8,
                    s_b + i * 2048 + wv * 512);
        __syncthreads();

        f16x8 af[4];
        #pragma unroll
        for (int im = 0; im < 4; ++im) {
            const float* ap = s_a + (wm * 64 + im * 16 + l15) * 32;
            const float4 f0 = *(const float4*)(ap + ca0 * 4);
            const float4 f1 = *(const float4*)(ap + (ca0 ^ 1) * 4);
            af[im] = f16x8{(_Float16)f0.x, (_Float16)f0.y, (_Float16)f0.z, (_Float16)f0.w,
                           (_Float16)f1.x, (_Float16)f1.y, (_Float16)f1.z, (_Float16)f1.w};
        }
        #pragma unroll
        for (int in_ = 0; in_ < 4; ++in_) {
            const f16x8 bf = *(const f16x8*)(s_b + (wn * 64 + in_ * 16 + l15) * 32 + cb * 8);
            #pragma unroll
            for (int im = 0; im < 4; ++im)
                acc[im][in_] = __builtin_amdgcn_mfma_f32_16x16x32_f16(af[im], bf, acc[im][in_], 0, 0, 0);
        }
    }

    if (bn < 8) {
        #pragma unroll
        for (int im = 0; im < 4; ++im)
            #pragma unroll
            for (int in_ = 0; in_ < 4; ++in_) {
                const int n = bn * 128 + wn * 64 + in_ * 16 + l15;
                const float bb = bias1[n];
                #pragma unroll
                for (int r = 0; r < 4; ++r) {
                    const int m = m0 + wm * 64 + im * 16 + q * 4 + r;
                    float v = acc[im][in_][r] + bb;
                    v = v > 0.f ? v : 0.f;
                    t1[(size_t)m * MLP + n] = (_Float16)v;
                }
            }
    } else {
        #pragma unroll
        for (int im = 0; im < 4; ++im)
            #pragma unroll
            for (int in_ = 0; in_ < 4; ++in_) {
                const int n = (bn - 8) * 128 + wn * 64 + in_ * 16 + l15;
                const float bb = bias2g[n];
                const int m4 = (m0 + wm * 64 + im * 16 + q * 4) >> 2;
                float4 v;
                v.x = acc[im][in_][0] + bb;
                v.y = acc[im][in_][1] + bb;
                v.z = acc[im][in_][2] + bb;
                v.w = acc[im][in_][3] + bb;
                *(float4*)(gperm + ((size_t)m4 * NG + n) * 4) = v;
            }
    }
}

// ---------------------------------------------------------------------------
// GEMM2 v2: h0[32768,128] = fp16(relu(t1 @ w2h.T + b2)). Tile 64x128,
// grid 512 -> 2 blocks/CU. Wave w: n-cols w*32 (2 frags), m 0..63 (4 frags).
// 4-chunk XOR-with-parity swizzle -> 2-way banks (free).
// ---------------------------------------------------------------------------
__global__ __launch_bounds__(256) void gemm2_kernel(
    const _Float16* __restrict__ t1, const _Float16* __restrict__ w2h,
    const float* __restrict__ b2, _Float16* __restrict__ h0buf)
{
    __shared__ _Float16 s_a[64 * 32];    // 4 KB
    __shared__ _Float16 s_b[128 * 32];   // 8 KB

    const int tid = threadIdx.x;
    const int m0  = blockIdx.x * 64;
    const int lane = tid & 63, wv = tid >> 6;
    const int l15 = lane & 15, q = lane >> 4;

    // staging: slot P -> row=P>>2, pch=P&3, logical c=(pch^row^(row>>2))&3
    const int rowS = tid >> 2;
    const int chS  = ((tid & 3) ^ (tid >> 2) ^ (tid >> 4)) & 3;
    // frag phys chunk: (q ^ l15 ^ (l15>>2)) & 3
    const int phF  = (q ^ l15 ^ (l15 >> 2)) & 3;

    f32x4 acc[4][2] = {};

    for (int kt = 0; kt < 32; ++kt) {
        __syncthreads();
        gload16(t1 + (size_t)(m0 + rowS) * MLP + kt * 32 + chS * 8,
                s_a + wv * 512);
        #pragma unroll
        for (int i = 0; i < 2; ++i) {
            const int row = i * 64 + rowS;
            const int c   = ((tid & 3) ^ row ^ (row >> 2)) & 3;
            gload16(w2h + (size_t)row * MLP + kt * 32 + c * 8,
                    s_b + i * 2048 + wv * 512);
        }
        __syncthreads();

        f16x8 af[4];
        #pragma unroll
        for (int im = 0; im < 4; ++im)
            af[im] = *(const f16x8*)(s_a + (im * 16 + l15) * 32 + phF * 8);
        #pragma unroll
        for (int in_ = 0; in_ < 2; ++in_) {
            const f16x8 bf = *(const f16x8*)(s_b + (wv * 32 + in_ * 16 + l15) * 32 + phF * 8);
            #pragma unroll
            for (int im = 0; im < 4; ++im)
                acc[im][in_] = __builtin_amdgcn_mfma_f32_16x16x32_f16(af[im], bf, acc[im][in_], 0, 0, 0);
        }
    }

    #pragma unroll
    for (int im = 0; im < 4; ++im)
        #pragma unroll
        for (int in_ = 0; in_ < 2; ++in_) {
            const int n = wv * 32 + in_ * 16 + l15;
            const float bb = b2[n];
            #pragma unroll
            for (int r = 0; r < 4; ++r) {
                const int m = m0 + im * 16 + q * 4 + r;
                float v = acc[im][in_][r] + bb;
                v = v > 0.f ? v : 0.f;
                h0buf[(size_t)m * H + n] = (_Float16)v;
            }
        }
}

// ---------------------------------------------------------------------------
// Recurrence (unchanged from round 3 — verified correct).
// ---------------------------------------------------------------------------
__global__ __launch_bounds__(512) void recur_kernel(
    const float* __restrict__ gperm, const _Float16* __restrict__ h0buf,
    const _Float16* __restrict__ whhf, const float* __restrict__ wc,
    const float* __restrict__ whp, const float* __restrict__ bhp,
    const float* __restrict__ lpr, float* __restrict__ out)
{
    __shared__ _Float16 s_whh[512 * 136];
    __shared__ _Float16 s_h[64 * 136];
    __shared__ float    s_p[128];
    __shared__ float    s_wc[1024];
    __shared__ float    s_whp[256];
    __shared__ float    s_bhp[2];

    const int tid = threadIdx.x;
    const int m0  = blockIdx.x * 64;
    const int lane = tid & 63, w = tid >> 6;
    const int l15 = lane & 15, q = lane >> 4;

    #pragma unroll
    for (int i = 0; i < 16; ++i) {
        const int cid = tid + i * 512;
        const int row = cid >> 4, ch = cid & 15;
        *(uint4*)(s_whh + row * 136 + ch * 8) = *(const uint4*)(whhf + row * H + ch * 8);
    }
    if (tid < 256) *(float4*)(s_wc + tid * 4)  = *(const float4*)(wc + tid * 4);
    if (tid < 64)  *(float4*)(s_whp + tid * 4) = *(const float4*)(whp + tid * 4);
    if (tid < 2)   s_bhp[tid] = bhp[tid];
    if (tid < 128) s_p[tid] = lpr[(size_t)m0 * 2 + tid];
    {
        const int row = tid >> 3, ch = tid & 7;
        *(uint4*)(s_h + row * 136 + ch * 16)     = *(const uint4*)(h0buf + (size_t)(m0 + row) * H + ch * 16);
        *(uint4*)(s_h + row * 136 + ch * 16 + 8) = *(const uint4*)(h0buf + (size_t)(m0 + row) * H + ch * 16 + 8);
    }

    f32x4 gb[4][4];
    #pragma unroll
    for (int im = 0; im < 4; ++im) {
        const int m4 = (m0 >> 2) + im * 4 + q;
        #pragma unroll
        for (int g = 0; g < 4; ++g) {
            const float4 v = *(const float4*)(gperm + ((size_t)m4 * NG + g * H + w * 16 + l15) * 4);
            gb[im][g] = f32x4{v.x, v.y, v.z, v.w};
        }
    }

    f32x4 cst[4] = {};

    __syncthreads();

    {
        const int part = tid & 3;
        const int j    = (tid >> 2) & 1;
        const int row  = tid >> 3;
        float sum = 0.f;
        #pragma unroll
        for (int u = 0; u < 4; ++u) {
            const f16x8 hv = *(const f16x8*)(s_h + row * 136 + part * 32 + u * 8);
            const float4* wp = (const float4*)(s_whp + j * H + part * 32 + u * 8);
            const float4 w0 = wp[0], w1 = wp[1];
            sum += (float)hv[0] * w0.x + (float)hv[1] * w0.y + (float)hv[2] * w0.z + (float)hv[3] * w0.w
                 + (float)hv[4] * w1.x + (float)hv[5] * w1.y + (float)hv[6] * w1.z + (float)hv[7] * w1.w;
        }
        sum += __shfl_down(sum, 2, 64);
        sum += __shfl_down(sum, 1, 64);
        if (part == 0) s_p[row * 2 + j] -= sum;
    }
    __syncthreads();

    float wc0[4], wc1[4], cg[4];
    #pragma unroll
    for (int g = 0; g < 4; ++g) {
        const int n = g * H + w * 16 + l15;
        wc0[g] = s_wc[n * 2];
        wc1[g] = s_wc[n * 2 + 1];
        cg[g]  = wc0[g] * s_bhp[0] + wc1[g] * s_bhp[1];
    }
    #pragma unroll
    for (int im = 0; im < 4; ++im)
        #pragma unroll
        for (int r = 0; r < 4; ++r) {
            const int mrow = im * 16 + q * 4 + r;
            const float pa = s_p[mrow * 2], pb = s_p[mrow * 2 + 1];
            #pragma unroll
            for (int g = 0; g < 4; ++g)
                gb[im][g][r] += pa * wc0[g] + pb * wc1[g];
        }

    for (int t = 0; t < SEQLEN; ++t) {
        f32x4 acc[4][4];
        #pragma unroll
        for (int kt = 0; kt < 4; ++kt) {
            f16x8 af[4];
            #pragma unroll
            for (int im = 0; im < 4; ++im)
                af[im] = *(const f16x8*)(s_h + (im * 16 + l15) * 136 + kt * 32 + q * 8);
            #pragma unroll
            for (int g = 0; g < 4; ++g) {
                const f16x8 bf = *(const f16x8*)(s_whh + (g * H + w * 16 + l15) * 136 + kt * 32 + q * 8);
                #pragma unroll
                for (int im = 0; im < 4; ++im)
                    acc[im][g] = __builtin_amdgcn_mfma_f32_16x16x32_f16(
                        af[im], bf, (kt == 0) ? gb[im][g] : acc[im][g], 0, 0, 0);
            }
        }
        __syncthreads();

        #pragma unroll
        for (int im = 0; im < 4; ++im) {
            #pragma unroll
            for (int r = 0; r < 4; ++r) {
                const int mrow = im * 16 + q * 4 + r;
                const float cc = sigf(acc[im][1][r]) * cst[im][r]
                               + sigf(acc[im][0][r]) * tanhfast(acc[im][2][r]);
                cst[im][r] = cc;
                const float hh = sigf(acc[im][3][r]) * tanhfast(cc);
                s_h[mrow * 136 + w * 16 + l15] = (_Float16)hh;
            }
        }
        if (t == 0) {
            #pragma unroll
            for (int im = 0; im < 4; ++im)
                #pragma unroll
                for (int r = 0; r < 4; ++r) {
                    const int mrow = im * 16 + q * 4 + r;
                    const float pa = s_p[mrow * 2], pb = s_p[mrow * 2 + 1];
                    #pragma unroll
                    for (int g = 0; g < 4; ++g)
                        gb[im][g][r] += cg[g] - (pa * wc0[g] + pb * wc1[g]);
                }
        }
        __syncthreads();

        {
            const int part = tid & 3;
            const int j    = (tid >> 2) & 1;
            const int row  = tid >> 3;
            float sum = 0.f;
            #pragma unroll
            for (int u = 0; u < 4; ++u) {
                const f16x8 hv = *(const f16x8*)(s_h + row * 136 + part * 32 + u * 8);
                const float4* wp = (const float4*)(s_whp + j * H + part * 32 + u * 8);
                const float4 w0 = wp[0], w1 = wp[1];
                sum += (float)hv[0] * w0.x + (float)hv[1] * w0.y + (float)hv[2] * w0.z + (float)hv[3] * w0.w
                     + (float)hv[4] * w1.x + (float)hv[5] * w1.y + (float)hv[6] * w1.z + (float)hv[7] * w1.w;
            }
            sum += __shfl_down(sum, 2, 64);
            sum += __shfl_down(sum, 1, 64);
            if (part == 0)
                out[(size_t)t * (BATCH * 2) + (size_t)(m0 + row) * 2 + j] = sum + s_bhp[j];
        }
    }
}

// ---------------------------------------------------------------------------
extern "C" void kernel_launch(void* const* d_in, const int* in_sizes, int n_in,
                              void* d_out, int out_size, void* d_ws, size_t ws_size,
                              hipStream_t stream)
{
    const float* last_pos_rel = (const float*)d_in[1];
    const float* enc          = (const float*)d_in[2];
    const float* zin          = (const float*)d_in[3];
    const float* W_ih         = (const float*)d_in[5];
    const float* W_hh         = (const float*)d_in[6];
    const float* b_ih         = (const float*)d_in[7];
    const float* b_hh         = (const float*)d_in[8];
    const float* W1           = (const float*)d_in[9];
    const float* b1           = (const float*)d_in[10];
    const float* W2           = (const float*)d_in[11];
    const float* b2           = (const float*)d_in[12];
    const float* W_sp         = (const float*)d_in[13];
    const float* b_sp         = (const float*)d_in[14];
    const float* W_hp         = (const float*)d_in[15];
    const float* b_hp         = (const float*)d_in[16];
    float* out = (float*)d_out;

    char* ws = (char*)d_ws;
    const bool big = (ws_size >= B_TOTAL);

    _Float16* wcat  = (_Float16*)(ws + (big ? B_WCAT_OFF  : S_WCAT_OFF));
    _Float16* w2h   = (_Float16*)(ws + (big ? B_W2H_OFF   : S_W2H_OFF));
    _Float16* whhf  = (_Float16*)(ws + (big ? B_WHHF_OFF  : S_WHHF_OFF));
    float*    wc    = (float*)(ws + (big ? B_WC_OFF    : S_WC_OFF));
    float*    bias2 = (float*)(ws + (big ? B_BIAS2_OFF : S_BIAS2_OFF));
    _Float16* t1    = (_Float16*)(ws + (big ? B_T1_OFF : S_T1_OFF));
    float*    gperm = (float*)(ws + (big ? B_GP_OFF : S_GP_OFF));
    _Float16* h0b   = (_Float16*)(ws + (big ? B_H0_OFF : S_H0_OFF));
    _Float16* zx16  = (_Float16*)(ws + B_ZX16_OFF);

    prep_kernel<<<dim3(1926), 256, 0, stream>>>(W_ih, W_hh, b_ih, b_hh, W1, W2, W_sp, b_sp,
                                                W_hp, big ? KP : ZX, wcat, w2h, whhf, wc, bias2);
    if (big) {
        zxcast_kernel<<<dim3(17408), 256, 0, stream>>>(enc, zin, zx16);
        gemm1_big_kernel<<<dim3(3072), 256, 0, stream>>>(zx16, wcat, b1, bias2, t1, gperm);
    } else {
        gemm1_small_kernel<<<dim3(3072), 256, 0, stream>>>(enc, zin, wcat, b1, bias2, t1, gperm);
    }
    gemm2_kernel<<<dim3(512), 256, 0, stream>>>(t1, w2h, b2, h0b);
    recur_kernel<<<dim3(512), 512, 0, stream>>>(gperm, h0b, whhf, wc, W_hp, b_hp,
                                                last_pos_rel, out);
}